// Round 6
// baseline (292.540 us; speedup 1.0000x reference)
//
#include <hip/hip_runtime.h>
#include <hip/hip_bf16.h>

#define NN 4096
typedef unsigned short u16;
typedef __bf16 bf16x8 __attribute__((ext_vector_type(8)));
typedef float f32x4 __attribute__((ext_vector_type(4)));
typedef u16 u16x8 __attribute__((ext_vector_type(8)));

typedef const __attribute__((address_space(1))) void* gptr_t;
typedef __attribute__((address_space(3))) void* lptr_t;

__device__ inline u16 bf16bits(float v) {
    __bf16 h = (__bf16)v;
    return __builtin_bit_cast(u16, h);
}
__device__ inline float bf16val(float v) {
    __bf16 h = (__bf16)v;
    return (float)h;
}
__device__ inline float b2f(u16 b) { return __uint_as_float(((unsigned)b) << 16); }

// ---------------- block reduction helper (256 threads / 4 waves) ----------------
__device__ inline float block_sum(float v, volatile float* sbuf) {
    int lane = threadIdx.x & 63, wv = threadIdx.x >> 6;
#pragma unroll
    for (int o = 32; o > 0; o >>= 1) v += __shfl_xor(v, o, 64);
    if (lane == 0) sbuf[wv] = v;
    __syncthreads();
    float r = sbuf[0] + sbuf[1] + sbuf[2] + sbuf[3];
    __syncthreads();
    return r;
}

// ---------------- normalize rows (float4), emit bf16 + sum-of-squares(bf16) ----------------
template <int D>
__global__ void normalize_kernel(const float* __restrict__ in, u16* __restrict__ outb,
                                 float* __restrict__ ssout) {
    __shared__ float sbuf[4];
    constexpr int NV = D / 4;
    int row = blockIdx.x, tid = threadIdx.x;
    const float4* x4 = (const float4*)(in + (size_t)row * D);
    float4 v = make_float4(0.f, 0.f, 0.f, 0.f);
    if (tid < NV) v = x4[tid];
    float s = v.x * v.x + v.y * v.y + v.z * v.z + v.w * v.w;
    float tot = block_sum(s, sbuf);
    float inv = 1.0f / fmaxf(sqrtf(tot), 1e-12f);
    float sb = 0.f;
    if (tid < NV) {
        float b0 = bf16val(v.x * inv), b1 = bf16val(v.y * inv);
        float b2 = bf16val(v.z * inv), b3 = bf16val(v.w * inv);
        ushort4 o;
        o.x = bf16bits(v.x * inv);
        o.y = bf16bits(v.y * inv);
        o.z = bf16bits(v.z * inv);
        o.w = bf16bits(v.w * inv);
        ((ushort4*)(outb + (size_t)row * D))[tid] = o;
        sb = b0 * b0 + b1 * b1 + b2 * b2 + b3 * b3;
    }
    float totb = block_sum(sb, sbuf);
    if (tid == 0) ssout[row] = totb;
}

// ---------------- merged symmetric Gram kernel, 256x256 tiles, 16 waves ----------------
// 408 blocks: [0,136) -> t (K=1024, W_P=exp(-d2)); [136,272) -> f; [272,408) -> g
// (K=512, S=sqrt(d2) + rowsum). Upper-triangle (by<=bx) 256x256 blocks; each block
// writes its tile and (if off-diagonal) the transposed tile, all coalesced via LDS.
#define TS 136  // epilogue LDS tile row stride in u16 (272B: 16B-aligned rows)
__launch_bounds__(1024, 4)
__global__ void gram_merged(const u16* __restrict__ tb, const u16* __restrict__ fb,
                            const u16* __restrict__ gb, const float* __restrict__ ss_t,
                            const float* __restrict__ ss_f, const float* __restrict__ ss_g,
                            u16* __restrict__ WP, u16* __restrict__ Sf, u16* __restrict__ Sg,
                            float* __restrict__ rsf, float* __restrict__ rsg) {
    // staging: A bufs [0,16384) u16, B bufs [16384,32768); epilogue: tile [0,17408), tileT [17408,34816)
    __shared__ __align__(16) u16 smem[34816];

    int bid = blockIdx.x;
    int which = (bid < 136) ? 0 : (bid < 272 ? 1 : 2);
    int lb = bid - which * 136;
    // triangular decode: (by, bx) with bx >= by, 16x16 tile grid
    int by = 0, rem = lb;
    while (rem >= 16 - by) { rem -= 16 - by; ++by; }
    int bx = by + rem;

    const u16* X = (which == 0) ? tb : (which == 1 ? fb : gb);
    const float* ss = (which == 0) ? ss_t : (which == 1 ? ss_f : ss_g);
    u16* outp = (which == 0) ? WP : (which == 1 ? Sf : Sg);
    float* rowsum = (which == 0) ? nullptr : (which == 1 ? rsf : rsg);
    const int K = (which == 0) ? 1024 : 512;
    const bool mode1 = (which != 0);
    const bool offdiag = (bx != by);

    const int tid = threadIdx.x;
    const int wv = tid >> 6, lane = tid & 63;
    const int wr = wv >> 2, wc = wv & 3;  // 4x4 wave grid, 64x64 per wave
    const int brow = by * 256, bcol = bx * 256;
    const int r = lane & 15, kc = lane >> 4;
    const int crow = lane >> 2;       // staging: row within 16-row chunk
    const int koff = (lane & 3) * 8;  // staging: element offset (16B granule)

    f32x4 acc[4][4];
#pragma unroll
    for (int mi = 0; mi < 4; ++mi)
#pragma unroll
        for (int ni = 0; ni < 4; ++ni) acc[mi][ni] = (f32x4){0.f, 0.f, 0.f, 0.f};

    // stage one 256x32 A-tile + 256x32 B-tile: 32 chunks of (16 rows x 32 k), 2 per wave
    auto STAGE = [&](int buf, int k0) {
#pragma unroll
        for (int cc = 0; cc < 2; ++cc) {
            int c = wv * 2 + cc;  // 0..31
            bool isB = c >= 16;
            int c16 = isB ? c - 16 : c;
            const u16* g = X + (size_t)((isB ? bcol : brow) + c16 * 16 + crow) * K + k0 + koff;
            int ldsoff = (isB ? 16384 : 0) + buf * 8192 + c16 * 512;
            __builtin_amdgcn_global_load_lds((gptr_t)g, (lptr_t)&smem[ldsoff], 16, 0, 0);
        }
    };

    const int NT = K / 32;
    STAGE(0, 0);
    __syncthreads();  // drains vmcnt: buf0 ready
    for (int t = 0; t < NT; ++t) {
        int cur = t & 1;
        if (t + 1 < NT) STAGE(cur ^ 1, (t + 1) * 32);

        bf16x8 af[4], bfr[4];
#pragma unroll
        for (int mi = 0; mi < 4; ++mi)
            af[mi] = *(const bf16x8*)&smem[cur * 8192 + (wr * 64 + mi * 16 + r) * 32 + kc * 8];
#pragma unroll
        for (int ni = 0; ni < 4; ++ni)
            bfr[ni] = *(const bf16x8*)&smem[16384 + cur * 8192 + (wc * 64 + ni * 16 + r) * 32 + kc * 8];
#pragma unroll
        for (int mi = 0; mi < 4; ++mi)
#pragma unroll
            for (int ni = 0; ni < 4; ++ni)
                acc[mi][ni] = __builtin_amdgcn_mfma_f32_16x16x32_bf16(af[mi], bfr[ni], acc[mi][ni], 0, 0, 0);

        __syncthreads();  // prefetch complete + all waves done reading buf[cur]
    }

    // epilogue: 4 quadrants of 128x128; owning 4 waves transform acc -> tile (+tileT),
    // then all 1024 threads write coalesced. C/D layout col=lane&15, row=(lane>>4)*4+reg.
    u16* tile = smem;
    u16* tileT = smem + 17408;
    const int q4 = lane >> 4;
    const int myqr = wr >> 1, myqc = wc >> 1;
#pragma unroll
    for (int qr = 0; qr < 2; ++qr) {
#pragma unroll
        for (int qc = 0; qc < 2; ++qc) {
            __syncthreads();  // previous quadrant's writes done reading LDS
            if (myqr == qr && myqc == qc) {
#pragma unroll
                for (int mi = 0; mi < 4; ++mi) {
#pragma unroll
                    for (int v = 0; v < 4; ++v) {
                        int rl = (wr & 1) * 64 + mi * 16 + q4 * 4 + v;
                        float ssi = ss[brow + qr * 128 + rl];
#pragma unroll
                        for (int ni = 0; ni < 4; ++ni) {
                            int cl = (wc & 1) * 64 + ni * 16 + r;
                            float d2 = fmaxf(ssi + ss[bcol + qc * 128 + cl] - 2.0f * acc[mi][ni][v], 0.f);
                            float o = mode1 ? sqrtf(d2) : __expf(-d2);
                            u16 ob = bf16bits(o);
                            tile[rl * TS + cl] = ob;
                            if (offdiag) tileT[cl * TS + rl] = ob;
                        }
                    }
                }
            }
            __syncthreads();
            // pass 1: rows of this quadrant
            {
                int rl = tid >> 3, hseg = tid & 7;
                const u16* srow = &tile[rl * TS + hseg * 16];
                u16x8 p0 = *(const u16x8*)srow;
                u16x8 p1 = *(const u16x8*)(srow + 8);
                u16* drow = outp + (size_t)(brow + qr * 128 + rl) * NN + bcol + qc * 128 + hseg * 16;
                *(u16x8*)drow = p0;
                *(u16x8*)(drow + 8) = p1;
                if (mode1) {
                    float rs = 0.f;
#pragma unroll
                    for (int u = 0; u < 8; ++u) rs += b2f(p0[u]) + b2f(p1[u]);
                    rs += __shfl_xor(rs, 1, 64);
                    rs += __shfl_xor(rs, 2, 64);
                    rs += __shfl_xor(rs, 4, 64);
                    if ((tid & 7) == 0) atomicAdd(&rowsum[brow + qr * 128 + rl], rs);
                }
            }
            // pass 2: mirrored rows (transposed tile)
            if (offdiag) {
                int cl = tid >> 3, hseg = tid & 7;
                const u16* srow = &tileT[cl * TS + hseg * 16];
                u16x8 p0 = *(const u16x8*)srow;
                u16x8 p1 = *(const u16x8*)(srow + 8);
                u16* drow = outp + (size_t)(bcol + qc * 128 + cl) * NN + brow + qr * 128 + hseg * 16;
                *(u16x8*)drow = p0;
                *(u16x8*)(drow + 8) = p1;
                if (mode1) {
                    float rs = 0.f;
#pragma unroll
                    for (int u = 0; u < 8; ++u) rs += b2f(p0[u]) + b2f(p1[u]);
                    rs += __shfl_xor(rs, 1, 64);
                    rs += __shfl_xor(rs, 2, 64);
                    rs += __shfl_xor(rs, 4, 64);
                    if ((tid & 7) == 0) atomicAdd(&rowsum[bcol + qc * 128 + cl], rs);
                }
            }
        }
    }
}

// ---------------- top-10 per row of W_P (bf16, ushort8 loads), same-id override ----------------
__global__ void topk_kernel(const u16* __restrict__ WP, const int* __restrict__ idx,
                            int* __restrict__ topk) {
    __shared__ unsigned long long sred[4];
    __shared__ unsigned long long sbest;
    int row = blockIdx.x, tid = threadIdx.x;
    int myid = idx[row];
    const u16x8* W8 = (const u16x8*)(WP + (size_t)row * NN);
    const int4* idx4 = (const int4*)idx;
    unsigned key[16];
#pragma unroll
    for (int a = 0; a < 2; ++a) {
        u16x8 w = W8[a * 256 + tid];
        int4 iA = idx4[a * 512 + tid * 2];
        int4 iB = idx4[a * 512 + tid * 2 + 1];
        int ids[8] = {iA.x, iA.y, iA.z, iA.w, iB.x, iB.y, iB.z, iB.w};
#pragma unroll
        for (int c = 0; c < 8; ++c)
            key[a * 8 + c] = (ids[c] == myid) ? 0x3F800000u : (((unsigned)w[c]) << 16);
    }
    int lane = tid & 63, wv = tid >> 6;
    for (int it = 0; it < 10; ++it) {
        unsigned long long best = 0;
#pragma unroll
        for (int a = 0; a < 2; ++a)
#pragma unroll
            for (int c = 0; c < 8; ++c) {
                unsigned j = (unsigned)(a * 2048 + tid * 8 + c);
                unsigned long long pk =
                    ((unsigned long long)key[a * 8 + c] << 32) | (0xFFFFFFFFu - j);
                if (pk > best) best = pk;
            }
#pragma unroll
        for (int o = 32; o > 0; o >>= 1) {
            unsigned long long t = __shfl_xor(best, o, 64);
            if (t > best) best = t;
        }
        if (lane == 0) sred[wv] = best;
        __syncthreads();
        if (tid == 0) {
            unsigned long long b = sred[0];
            for (int w2 = 1; w2 < 4; ++w2)
                if (sred[w2] > b) b = sred[w2];
            sbest = b;
        }
        __syncthreads();
        unsigned jstar = 0xFFFFFFFFu - (unsigned)(sbest & 0xFFFFFFFFu);
        if (tid == 0) topk[row * 10 + it] = (int)jstar;
        if (((jstar >> 3) & 255u) == (unsigned)tid) {
            unsigned slot = ((jstar >> 11) << 3) | (jstar & 7u);
#pragma unroll
            for (int a = 0; a < 16; ++a)
                if ((unsigned)a == slot) key[a] = 0u;
        }
        __syncthreads();
    }
}

// ---------------- mutual-kNN adjacency: thread per (i,a); sentinel -1 slots ----------------
__global__ void mutual_kernel(const int* __restrict__ topk, int* __restrict__ nbr,
                              int* __restrict__ deg) {
    int gid = blockIdx.x * 256 + threadIdx.x;
    if (gid >= NN * 10) return;
    int i = gid / 10, a = gid - i * 10;
    int j = topk[i * 10 + a];
    bool mut = false;
#pragma unroll
    for (int b = 0; b < 10; ++b) mut = mut || (topk[j * 10 + b] == i);
    nbr[gid] = mut ? j : -1;
    if (mut) atomicAdd(&deg[i], 1);
}

// ---------------- W_C_tilda: thread per (m,a) ----------------
__global__ void tilda_kernel(const int* __restrict__ nbr, const int* __restrict__ deg,
                             float* __restrict__ tvals) {
    int gid = blockIdx.x * 256 + threadIdx.x;
    if (gid >= NN * 10) return;
    int m = gid / 10;
    int j = nbr[gid];
    if (j < 0) { tvals[gid] = 0.f; return; }
    int am[10], aj[10];
#pragma unroll
    for (int p = 0; p < 10; ++p) am[p] = nbr[m * 10 + p];
#pragma unroll
    for (int p = 0; p < 10; ++p) aj[p] = nbr[j * 10 + p];
    int cnt = 0;
#pragma unroll
    for (int p = 0; p < 10; ++p)
#pragma unroll
        for (int qq = 0; qq < 10; ++qq)
            cnt += (am[p] >= 0 && am[p] == aj[qq]) ? 1 : 0;
    int dm = deg[m];
    float dv = (float)(dm > 1 ? dm : 1);
    tvals[gid] = (float)cnt / dv;
}

// ---------------- W_C_hat: thread per (i,h); emit 10 slots verbatim ----------------
__global__ void hat_kernel(const int* __restrict__ topk, const int* __restrict__ nbr,
                           const float* __restrict__ tvals, int* __restrict__ hcols,
                           float* __restrict__ hvals) {
    int gid = blockIdx.x * 256 + threadIdx.x;
    if (gid >= NN * 5) return;
    int i = gid / 5, h = gid - i * 5;
    int m = topk[i * 10 + h];
#pragma unroll
    for (int a = 0; a < 10; ++a) {
        int j = nbr[m * 10 + a];
        int slot = i * 50 + h * 10 + a;
        hcols[slot] = j;
        hvals[slot] = (j >= 0) ? tvals[m * 10 + a] * 0.2f : 0.f;
    }
}

// ---------------- fused: per-row inv-mean + logsumexp + RC dense (W_P part) + KL ----------------
__global__ void fused_dense_kernel(const u16* __restrict__ Sf, const u16* __restrict__ Sg,
                                   const u16* __restrict__ WP, const float* __restrict__ rsf,
                                   const float* __restrict__ rsg, double* __restrict__ acc) {
    __shared__ float sbuf[4];
    int row = blockIdx.x, tid = threadIdx.x;
    float imf = (float)NN / rsf[row];
    float img = (float)NN / rsg[row];
    const u16x8* f8 = (const u16x8*)(Sf + (size_t)row * NN);
    const u16x8* g8 = (const u16x8*)(Sg + (size_t)row * NN);
    const u16x8* w8 = (const u16x8*)(WP + (size_t)row * NN);
    u16x8 fr[2], gr[2];
#pragma unroll
    for (int a = 0; a < 2; ++a) {
        fr[a] = f8[a * 256 + tid];
        gr[a] = g8[a * 256 + tid];
    }
    float vf[16], vg[16];
#pragma unroll
    for (int a = 0; a < 2; ++a)
#pragma unroll
        for (int c = 0; c < 8; ++c) {
            vf[a * 8 + c] = b2f(fr[a][c]) * imf;
            vg[a * 8 + c] = b2f(gr[a][c]) * img;
        }
    float ef = 0.f, eg = 0.f;
#pragma unroll
    for (int a = 0; a < 16; ++a) {
        ef += __expf(-vf[a]);
        eg += __expf(-vg[a]);
    }
    float lf = logf(block_sum(ef, sbuf));
    float lg = logf(block_sum(eg, sbuf));
    u16x8 wr2[2];
#pragma unroll
    for (int a = 0; a < 2; ++a) wr2[a] = w8[a * 256 + tid];
    float af = 0.f, ag = 0.f, akl = 0.f;
#pragma unroll
    for (int a = 0; a < 2; ++a) {
#pragma unroll
        for (int c = 0; c < 8; ++c) {
            int j = a * 2048 + tid * 8 + c;
            float wp = b2f(wr2[a][c]);
            float sf = vf[a * 8 + c], sg = vg[a * 8 + c];
            if (j != row) {
                float t = fmaxf(1.f - sf, 0.f);
                float pu = t * t;
                float gq = sf * sf - pu;
                af += pu + 0.5f * gq * wp;
                t = fmaxf(1.f - sg, 0.f);
                pu = t * t;
                gq = sg * sg - pu;
                ag += pu + 0.5f * gq * wp;
            }
            float lq = -sf - lf;
            float lp = -sg - lg;
            float pp = __expf(lp);
            akl += pp * (lp - lq);
        }
    }
    float tf = block_sum(af, sbuf);
    float tg2 = block_sum(ag, sbuf);
    float tk = block_sum(akl, sbuf);
    if (tid == 0) {
        int bank = (row & 15) * 3;
        atomicAdd(&acc[bank + 0], (double)tf);
        atomicAdd(&acc[bank + 1], (double)tg2);
        atomicAdd(&acc[bank + 2], (double)tk);
    }
}

// ---------------- sparse W_C correction: wave per row, lanes 0..49 over hat slots ----------------
__global__ void sparse_kernel(const u16* __restrict__ Sf, const u16* __restrict__ Sg,
                              const int* __restrict__ hcols, const float* __restrict__ hvals,
                              const float* __restrict__ rsf, const float* __restrict__ rsg,
                              double* __restrict__ acc) {
    __shared__ float sbuf[4];
    int lane = threadIdx.x & 63, wv = threadIdx.x >> 6;
    int i = blockIdx.x * 4 + wv;
    float cf = 0.f, cg = 0.f;
    if (lane < 50) {
        int j = hcols[i * 50 + lane];
        if (j >= 0 && j != i) {
            float v = hvals[i * 50 + lane];
            float imfi = (float)NN / rsf[i];
            float imgi = (float)NN / rsg[i];
            float s1 = b2f(Sf[(size_t)i * NN + j]) * imfi;
            float s2 = b2f(Sf[(size_t)j * NN + i]) * ((float)NN / rsf[j]);
            float t1 = fmaxf(1.f - s1, 0.f), t2 = fmaxf(1.f - s2, 0.f);
            cf = v * ((s1 * s1 - t1 * t1) + (s2 * s2 - t2 * t2));
            s1 = b2f(Sg[(size_t)i * NN + j]) * imgi;
            s2 = b2f(Sg[(size_t)j * NN + i]) * ((float)NN / rsg[j]);
            t1 = fmaxf(1.f - s1, 0.f);
            t2 = fmaxf(1.f - s2, 0.f);
            cg = v * ((s1 * s1 - t1 * t1) + (s2 * s2 - t2 * t2));
        }
    }
    float tf = block_sum(cf, sbuf);
    float tg = block_sum(cg, sbuf);
    if (threadIdx.x == 0) {
        int bank = (blockIdx.x & 15) * 3;
        atomicAdd(&acc[bank + 0], (double)(0.25f * tf));
        atomicAdd(&acc[bank + 1], (double)(0.25f * tg));
    }
}

__global__ void finalize_kernel(const double* __restrict__ acc, float* __restrict__ out) {
    if (threadIdx.x == 0) {
        double a0 = 0.0, a1 = 0.0, a2 = 0.0;
        for (int b = 0; b < 16; ++b) {
            a0 += acc[b * 3 + 0];
            a1 += acc[b * 3 + 1];
            a2 += acc[b * 3 + 2];
        }
        double denom = (double)NN * (double)(NN - 1);
        double rcf = a0 / denom, rcg = a1 / denom;
        double rc = 0.5 * (rcf + rcg);
        double kl = a2 / (double)NN;
        out[0] = (float)rc;
        out[1] = (float)kl;
        out[2] = (float)(rc + kl);
    }
}

extern "C" void kernel_launch(void* const* d_in, const int* in_sizes, int n_in, void* d_out,
                              int out_size, void* d_ws, size_t ws_size, hipStream_t stream) {
    const float* s_f = (const float*)d_in[0];
    const float* s_g = (const float*)d_in[1];
    const float* t_g = (const float*)d_in[2];
    const int* idx = (const int*)d_in[3];
    float* out = (float*)d_out;

    char* base = (char*)d_ws;
    size_t off = 0;
    auto alloc = [&](size_t b) {
        char* p = base + off;
        off = (off + b + 255) & ~(size_t)255;
        return p;
    };
    double* acc = (double*)alloc(16 * 3 * 8);  // 16 banks x 3 doubles
    float* rowsum_f = (float*)alloc(NN * 4);
    float* rowsum_g = (float*)alloc(NN * 4);
    int* deg = (int*)alloc(NN * 4);
    size_t zero_bytes = off;  // acc + rowsums + deg zeroed each call
    u16* tb = (u16*)alloc((size_t)NN * 1024 * 2);
    u16* fb = (u16*)alloc((size_t)NN * 512 * 2);
    u16* gb = (u16*)alloc((size_t)NN * 512 * 2);
    float* ss_t = (float*)alloc(NN * 4);
    float* ss_f = (float*)alloc(NN * 4);
    float* ss_g = (float*)alloc(NN * 4);
    u16* WP = (u16*)alloc((size_t)NN * NN * 2);
    u16* Sf = (u16*)alloc((size_t)NN * NN * 2);
    u16* Sg = (u16*)alloc((size_t)NN * NN * 2);
    int* topk = (int*)alloc(NN * 10 * 4);
    int* nbr = (int*)alloc(NN * 10 * 4);
    float* tvals = (float*)alloc(NN * 10 * 4);
    int* hcols = (int*)alloc(NN * 50 * 4);
    float* hvals = (float*)alloc(NN * 50 * 4);

    hipMemsetAsync(d_ws, 0, zero_bytes, stream);

    normalize_kernel<1024><<<NN, 256, 0, stream>>>(t_g, tb, ss_t);
    normalize_kernel<512><<<NN, 256, 0, stream>>>(s_f, fb, ss_f);
    normalize_kernel<512><<<NN, 256, 0, stream>>>(s_g, gb, ss_g);

    gram_merged<<<408, 1024, 0, stream>>>(tb, fb, gb, ss_t, ss_f, ss_g, WP, Sf, Sg,
                                          rowsum_f, rowsum_g);

    topk_kernel<<<NN, 256, 0, stream>>>(WP, idx, topk);
    mutual_kernel<<<(NN * 10 + 255) / 256, 256, 0, stream>>>(topk, nbr, deg);
    tilda_kernel<<<(NN * 10 + 255) / 256, 256, 0, stream>>>(nbr, deg, tvals);
    hat_kernel<<<(NN * 5 + 255) / 256, 256, 0, stream>>>(topk, nbr, tvals, hcols, hvals);

    fused_dense_kernel<<<NN, 256, 0, stream>>>(Sf, Sg, WP, rowsum_f, rowsum_g, acc);
    sparse_kernel<<<NN / 4, 256, 0, stream>>>(Sf, Sg, hcols, hvals, rowsum_f, rowsum_g, acc);
    finalize_kernel<<<1, 64, 0, stream>>>(acc, out);
}

// Round 7
// 229.104 us; speedup vs baseline: 1.2769x; 1.2769x over previous
//
#include <hip/hip_runtime.h>
#include <hip/hip_bf16.h>

#define NN 4096
typedef unsigned short u16;
typedef __bf16 bf16x8 __attribute__((ext_vector_type(8)));
typedef float f32x4 __attribute__((ext_vector_type(4)));
typedef u16 u16x8 __attribute__((ext_vector_type(8)));

typedef const __attribute__((address_space(1))) void* gptr_t;
typedef __attribute__((address_space(3))) void* lptr_t;

__device__ inline u16 bf16bits(float v) {
    __bf16 h = (__bf16)v;
    return __builtin_bit_cast(u16, h);
}
__device__ inline float bf16val(float v) {
    __bf16 h = (__bf16)v;
    return (float)h;
}
__device__ inline float b2f(u16 b) { return __uint_as_float(((unsigned)b) << 16); }

// ---------------- block reduction helper (256 threads / 4 waves) ----------------
__device__ inline float block_sum(float v, volatile float* sbuf) {
    int lane = threadIdx.x & 63, wv = threadIdx.x >> 6;
#pragma unroll
    for (int o = 32; o > 0; o >>= 1) v += __shfl_xor(v, o, 64);
    if (lane == 0) sbuf[wv] = v;
    __syncthreads();
    float r = sbuf[0] + sbuf[1] + sbuf[2] + sbuf[3];
    __syncthreads();
    return r;
}

// ---------------- normalize rows (float4), emit bf16 + sum-of-squares(bf16) ----------------
template <int D>
__global__ void normalize_kernel(const float* __restrict__ in, u16* __restrict__ outb,
                                 float* __restrict__ ssout) {
    __shared__ float sbuf[4];
    constexpr int NV = D / 4;
    int row = blockIdx.x, tid = threadIdx.x;
    const float4* x4 = (const float4*)(in + (size_t)row * D);
    float4 v = make_float4(0.f, 0.f, 0.f, 0.f);
    if (tid < NV) v = x4[tid];
    float s = v.x * v.x + v.y * v.y + v.z * v.z + v.w * v.w;
    float tot = block_sum(s, sbuf);
    float inv = 1.0f / fmaxf(sqrtf(tot), 1e-12f);
    float sb = 0.f;
    if (tid < NV) {
        float b0 = bf16val(v.x * inv), b1 = bf16val(v.y * inv);
        float b2 = bf16val(v.z * inv), b3 = bf16val(v.w * inv);
        ushort4 o;
        o.x = bf16bits(v.x * inv);
        o.y = bf16bits(v.y * inv);
        o.z = bf16bits(v.z * inv);
        o.w = bf16bits(v.w * inv);
        ((ushort4*)(outb + (size_t)row * D))[tid] = o;
        sb = b0 * b0 + b1 * b1 + b2 * b2 + b3 * b3;
    }
    float totb = block_sum(sb, sbuf);
    if (tid == 0) ssout[row] = totb;
}

// ---------------- merged symmetric Gram kernel, 128x128 tiles, 4 waves ----------------
// 1584 blocks = 3 segments x 528 triangle blocks (32x32 grid, bx>=by).
// Per-matrix XCD swizzle: 528 = 8*66, each XCD gets 66 contiguous logical blocks
// of EACH matrix (balanced t/f/g load + A-panel L2 locality).
// K-loop: 3-buffer staging, counted vmcnt(4) (never 0 mid-loop), raw barriers.
#define TS 132  // epilogue LDS tile row stride in u16
__launch_bounds__(256)
__global__ void gram_merged(const u16* __restrict__ tb, const u16* __restrict__ fb,
                            const u16* __restrict__ gb, const float* __restrict__ ss_t,
                            const float* __restrict__ ss_f, const float* __restrict__ ss_g,
                            u16* __restrict__ WP, u16* __restrict__ Sf, u16* __restrict__ Sg,
                            float* __restrict__ rsf, float* __restrict__ rsg) {
    // staging: A bufs [0,12288) u16 (3 x 4096), B bufs [12288,24576); epilogue tile overlaps base.
    __shared__ __align__(16) u16 smem[24576];  // 49152 B

    int bid = blockIdx.x;
    int seg = (bid < 528) ? 0 : (bid < 1056 ? 1 : 2);
    int p = bid - seg * 528;
    int l = (p & 7) * 66 + (p >> 3);  // bijective XCD swizzle within segment
    int by = 0, rem = l;
    while (rem >= 32 - by) { rem -= 32 - by; ++by; }
    int bx = by + rem;

    const u16* X = (seg == 0) ? tb : (seg == 1 ? fb : gb);
    const float* ss = (seg == 0) ? ss_t : (seg == 1 ? ss_f : ss_g);
    u16* outp = (seg == 0) ? WP : (seg == 1 ? Sf : Sg);
    float* rowsum = (seg == 0) ? nullptr : (seg == 1 ? rsf : rsg);
    const int K = (seg == 0) ? 1024 : 512;
    const bool mode1 = (seg != 0);
    const bool offdiag = (bx != by);

    const int tid = threadIdx.x;
    const int wv = tid >> 6, lane = tid & 63;
    const int wr = wv >> 1, wc = wv & 1;
    const int brow = by * 128, bcol = bx * 128;
    const int r = lane & 15, kc = lane >> 4;
    const int crow = lane >> 2;       // staging: row within 16-row chunk
    const int koff = (lane & 3) * 8;  // staging: element offset (16B granule)

    f32x4 acc[4][4];
#pragma unroll
    for (int mi = 0; mi < 4; ++mi)
#pragma unroll
        for (int ni = 0; ni < 4; ++ni) acc[mi][ni] = (f32x4){0.f, 0.f, 0.f, 0.f};

    // stage one 128x32 A-tile + B-tile into buffer buf: 8 chunks each, 2 per wave.
    // per-wave vmem ops per STAGE call = 4 (used by the vmcnt(4) accounting below).
    auto STAGE = [&](int buf, int k0) {
#pragma unroll
        for (int cc = 0; cc < 2; ++cc) {
            int c = wv * 2 + cc;  // c in [0,8)
            const u16* ga = X + (size_t)(brow + c * 16 + crow) * K + k0 + koff;
            const u16* gbp = X + (size_t)(bcol + c * 16 + crow) * K + k0 + koff;
            __builtin_amdgcn_global_load_lds((gptr_t)ga, (lptr_t)&smem[buf * 4096 + c * 512], 16, 0, 0);
            __builtin_amdgcn_global_load_lds((gptr_t)gbp, (lptr_t)&smem[12288 + buf * 4096 + c * 512], 16, 0, 0);
        }
    };

    const int NT = K / 32;
    STAGE(0, 0);
    STAGE(1, 32);
    for (int t = 0; t < NT; ++t) {
        int cur = t % 3;
        // B1: my 4 loads for buf[cur] complete (4 newer ones for t+1 stay in flight)
        if (t == NT - 1) asm volatile("s_waitcnt vmcnt(0)" ::: "memory");
        else             asm volatile("s_waitcnt vmcnt(4)" ::: "memory");
        __builtin_amdgcn_sched_barrier(0);
        __builtin_amdgcn_s_barrier();  // all waves' buf[cur] loads landed

        bf16x8 af[4], bfr[4];
#pragma unroll
        for (int mi = 0; mi < 4; ++mi)
            af[mi] = *(const bf16x8*)&smem[cur * 4096 + (wr * 64 + mi * 16 + r) * 32 + kc * 8];
#pragma unroll
        for (int ni = 0; ni < 4; ++ni)
            bfr[ni] = *(const bf16x8*)&smem[12288 + cur * 4096 + (wc * 64 + ni * 16 + r) * 32 + kc * 8];

        if (t + 2 < NT) STAGE((t + 2) % 3, (t + 2) * 32);  // into buf[(t-1)%3], safe after B1

        asm volatile("s_waitcnt lgkmcnt(0)" ::: "memory");  // frags in regs
        __builtin_amdgcn_sched_barrier(0);                  // rule #18 fence
        __builtin_amdgcn_s_barrier();  // B2: all waves done reading buf[cur]

#pragma unroll
        for (int mi = 0; mi < 4; ++mi)
#pragma unroll
            for (int ni = 0; ni < 4; ++ni)
                acc[mi][ni] = __builtin_amdgcn_mfma_f32_16x16x32_bf16(af[mi], bfr[ni], acc[mi][ni], 0, 0, 0);
    }
    __syncthreads();  // loop done everywhere; tile may overwrite staging LDS

    // epilogue: transform acc -> bf16 LDS tile (C/D layout col=lane&15, row=(lane>>4)*4+reg)
    u16* tile = smem;
    const int q = lane >> 4;
#pragma unroll
    for (int mi = 0; mi < 4; ++mi) {
#pragma unroll
        for (int v = 0; v < 4; ++v) {
            int rl = wr * 64 + mi * 16 + q * 4 + v;
            float ssi = ss[brow + rl];
#pragma unroll
            for (int ni = 0; ni < 4; ++ni) {
                int cl = wc * 64 + ni * 16 + r;
                float d2 = fmaxf(ssi + ss[bcol + cl] - 2.0f * acc[mi][ni][v], 0.f);
                float o = mode1 ? sqrtf(d2) : __expf(-d2);
                tile[rl * TS + cl] = bf16bits(o);
            }
        }
    }
    __syncthreads();

    // pass 1: coalesced writeout of tile rows + row sums
    {
        int rl = tid >> 1, hf = tid & 1;
        const u16* srow = &tile[rl * TS + hf * 64];
        u16* drow = outp + (size_t)(brow + rl) * NN + bcol + hf * 64;
        float rs = 0.f;
#pragma unroll
        for (int i = 0; i < 8; ++i) {
            ushort4 aa = *(const ushort4*)(srow + i * 8);
            ushort4 bb = *(const ushort4*)(srow + i * 8 + 4);
            u16x8 pk = {aa.x, aa.y, aa.z, aa.w, bb.x, bb.y, bb.z, bb.w};
            *(u16x8*)(drow + i * 8) = pk;
            if (mode1)
                rs += b2f(aa.x) + b2f(aa.y) + b2f(aa.z) + b2f(aa.w) +
                      b2f(bb.x) + b2f(bb.y) + b2f(bb.z) + b2f(bb.w);
        }
        if (mode1) {
            rs += __shfl_xor(rs, 1, 64);
            if (hf == 0) atomicAdd(&rowsum[brow + rl], rs);
        }
    }

    // pass 2 (off-diagonal blocks): transposed writeout + col sums
    if (offdiag) {
        int c = tid >> 1, hf = tid & 1;
        u16* drow = outp + (size_t)(bcol + c) * NN + brow + hf * 64;
        float rs = 0.f;
#pragma unroll
        for (int s = 0; s < 8; ++s) {
            u16 g[8];
#pragma unroll
            for (int u = 0; u < 8; ++u) g[u] = tile[(hf * 64 + s * 8 + u) * TS + c];
            u16x8 pk = {g[0], g[1], g[2], g[3], g[4], g[5], g[6], g[7]};
            *(u16x8*)(drow + s * 8) = pk;
            if (mode1)
#pragma unroll
                for (int u = 0; u < 8; ++u) rs += b2f(g[u]);
        }
        if (mode1) {
            rs += __shfl_xor(rs, 1, 64);
            if (hf == 0) atomicAdd(&rowsum[bcol + c], rs);
        }
    }
}

// ---------------- top-10 per row of W_P (bf16, ushort8 loads), same-id override ----------------
__global__ void topk_kernel(const u16* __restrict__ WP, const int* __restrict__ idx,
                            int* __restrict__ topk) {
    __shared__ unsigned long long sred[4];
    __shared__ unsigned long long sbest;
    int row = blockIdx.x, tid = threadIdx.x;
    int myid = idx[row];
    const u16x8* W8 = (const u16x8*)(WP + (size_t)row * NN);
    const int4* idx4 = (const int4*)idx;
    unsigned key[16];
#pragma unroll
    for (int a = 0; a < 2; ++a) {
        u16x8 w = W8[a * 256 + tid];
        int4 iA = idx4[a * 512 + tid * 2];
        int4 iB = idx4[a * 512 + tid * 2 + 1];
        int ids[8] = {iA.x, iA.y, iA.z, iA.w, iB.x, iB.y, iB.z, iB.w};
#pragma unroll
        for (int c = 0; c < 8; ++c)
            key[a * 8 + c] = (ids[c] == myid) ? 0x3F800000u : (((unsigned)w[c]) << 16);
    }
    int lane = tid & 63, wv = tid >> 6;
    for (int it = 0; it < 10; ++it) {
        unsigned long long best = 0;
#pragma unroll
        for (int a = 0; a < 2; ++a)
#pragma unroll
            for (int c = 0; c < 8; ++c) {
                unsigned j = (unsigned)(a * 2048 + tid * 8 + c);
                unsigned long long pk =
                    ((unsigned long long)key[a * 8 + c] << 32) | (0xFFFFFFFFu - j);
                if (pk > best) best = pk;
            }
#pragma unroll
        for (int o = 32; o > 0; o >>= 1) {
            unsigned long long t = __shfl_xor(best, o, 64);
            if (t > best) best = t;
        }
        if (lane == 0) sred[wv] = best;
        __syncthreads();
        if (tid == 0) {
            unsigned long long b = sred[0];
            for (int w2 = 1; w2 < 4; ++w2)
                if (sred[w2] > b) b = sred[w2];
            sbest = b;
        }
        __syncthreads();
        unsigned jstar = 0xFFFFFFFFu - (unsigned)(sbest & 0xFFFFFFFFu);
        if (tid == 0) topk[row * 10 + it] = (int)jstar;
        if (((jstar >> 3) & 255u) == (unsigned)tid) {
            unsigned slot = ((jstar >> 11) << 3) | (jstar & 7u);
#pragma unroll
            for (int a = 0; a < 16; ++a)
                if ((unsigned)a == slot) key[a] = 0u;
        }
        __syncthreads();
    }
}

// ---------------- mutual-kNN adjacency: thread per (i,a); sentinel -1 slots ----------------
__global__ void mutual_kernel(const int* __restrict__ topk, int* __restrict__ nbr,
                              int* __restrict__ deg) {
    int gid = blockIdx.x * 256 + threadIdx.x;
    if (gid >= NN * 10) return;
    int i = gid / 10, a = gid - i * 10;
    int j = topk[i * 10 + a];
    bool mut = false;
#pragma unroll
    for (int b = 0; b < 10; ++b) mut = mut || (topk[j * 10 + b] == i);
    nbr[gid] = mut ? j : -1;
    if (mut) atomicAdd(&deg[i], 1);
}

// ---------------- W_C_tilda: thread per (m,a) ----------------
__global__ void tilda_kernel(const int* __restrict__ nbr, const int* __restrict__ deg,
                             float* __restrict__ tvals) {
    int gid = blockIdx.x * 256 + threadIdx.x;
    if (gid >= NN * 10) return;
    int m = gid / 10;
    int j = nbr[gid];
    if (j < 0) { tvals[gid] = 0.f; return; }
    int am[10], aj[10];
#pragma unroll
    for (int p = 0; p < 10; ++p) am[p] = nbr[m * 10 + p];
#pragma unroll
    for (int p = 0; p < 10; ++p) aj[p] = nbr[j * 10 + p];
    int cnt = 0;
#pragma unroll
    for (int p = 0; p < 10; ++p)
#pragma unroll
        for (int qq = 0; qq < 10; ++qq)
            cnt += (am[p] >= 0 && am[p] == aj[qq]) ? 1 : 0;
    int dm = deg[m];
    float dv = (float)(dm > 1 ? dm : 1);
    tvals[gid] = (float)cnt / dv;
}

// ---------------- W_C_hat: thread per (i,h); emit 10 slots verbatim ----------------
__global__ void hat_kernel(const int* __restrict__ topk, const int* __restrict__ nbr,
                           const float* __restrict__ tvals, int* __restrict__ hcols,
                           float* __restrict__ hvals) {
    int gid = blockIdx.x * 256 + threadIdx.x;
    if (gid >= NN * 5) return;
    int i = gid / 5, h = gid - i * 5;
    int m = topk[i * 10 + h];
#pragma unroll
    for (int a = 0; a < 10; ++a) {
        int j = nbr[m * 10 + a];
        int slot = i * 50 + h * 10 + a;
        hcols[slot] = j;
        hvals[slot] = (j >= 0) ? tvals[m * 10 + a] * 0.2f : 0.f;
    }
}

// ---------------- fused: per-row inv-mean + logsumexp + RC dense (W_P part) + KL ----------------
__global__ void fused_dense_kernel(const u16* __restrict__ Sf, const u16* __restrict__ Sg,
                                   const u16* __restrict__ WP, const float* __restrict__ rsf,
                                   const float* __restrict__ rsg, double* __restrict__ acc) {
    __shared__ float sbuf[4];
    int row = blockIdx.x, tid = threadIdx.x;
    float imf = (float)NN / rsf[row];
    float img = (float)NN / rsg[row];
    const u16x8* f8 = (const u16x8*)(Sf + (size_t)row * NN);
    const u16x8* g8 = (const u16x8*)(Sg + (size_t)row * NN);
    const u16x8* w8 = (const u16x8*)(WP + (size_t)row * NN);
    u16x8 fr[2], gr[2];
#pragma unroll
    for (int a = 0; a < 2; ++a) {
        fr[a] = f8[a * 256 + tid];
        gr[a] = g8[a * 256 + tid];
    }
    float vf[16], vg[16];
#pragma unroll
    for (int a = 0; a < 2; ++a)
#pragma unroll
        for (int c = 0; c < 8; ++c) {
            vf[a * 8 + c] = b2f(fr[a][c]) * imf;
            vg[a * 8 + c] = b2f(gr[a][c]) * img;
        }
    float ef = 0.f, eg = 0.f;
#pragma unroll
    for (int a = 0; a < 16; ++a) {
        ef += __expf(-vf[a]);
        eg += __expf(-vg[a]);
    }
    float lf = logf(block_sum(ef, sbuf));
    float lg = logf(block_sum(eg, sbuf));
    u16x8 wr2[2];
#pragma unroll
    for (int a = 0; a < 2; ++a) wr2[a] = w8[a * 256 + tid];
    float af = 0.f, ag = 0.f, akl = 0.f;
#pragma unroll
    for (int a = 0; a < 2; ++a) {
#pragma unroll
        for (int c = 0; c < 8; ++c) {
            int j = a * 2048 + tid * 8 + c;
            float wp = b2f(wr2[a][c]);
            float sf = vf[a * 8 + c], sg = vg[a * 8 + c];
            if (j != row) {
                float t = fmaxf(1.f - sf, 0.f);
                float pu = t * t;
                float gq = sf * sf - pu;
                af += pu + 0.5f * gq * wp;
                t = fmaxf(1.f - sg, 0.f);
                pu = t * t;
                gq = sg * sg - pu;
                ag += pu + 0.5f * gq * wp;
            }
            float lq = -sf - lf;
            float lp = -sg - lg;
            float pp = __expf(lp);
            akl += pp * (lp - lq);
        }
    }
    float tf = block_sum(af, sbuf);
    float tg2 = block_sum(ag, sbuf);
    float tk = block_sum(akl, sbuf);
    if (tid == 0) {
        int bank = (row & 15) * 3;
        atomicAdd(&acc[bank + 0], (double)tf);
        atomicAdd(&acc[bank + 1], (double)tg2);
        atomicAdd(&acc[bank + 2], (double)tk);
    }
}

// ---------------- sparse W_C correction: wave per row, lanes 0..49 over hat slots ----------------
__global__ void sparse_kernel(const u16* __restrict__ Sf, const u16* __restrict__ Sg,
                              const int* __restrict__ hcols, const float* __restrict__ hvals,
                              const float* __restrict__ rsf, const float* __restrict__ rsg,
                              double* __restrict__ acc) {
    __shared__ float sbuf[4];
    int lane = threadIdx.x & 63, wv = threadIdx.x >> 6;
    int i = blockIdx.x * 4 + wv;
    float cf = 0.f, cg = 0.f;
    if (lane < 50) {
        int j = hcols[i * 50 + lane];
        if (j >= 0 && j != i) {
            float v = hvals[i * 50 + lane];
            float imfi = (float)NN / rsf[i];
            float imgi = (float)NN / rsg[i];
            float s1 = b2f(Sf[(size_t)i * NN + j]) * imfi;
            float s2 = b2f(Sf[(size_t)j * NN + i]) * ((float)NN / rsf[j]);
            float t1 = fmaxf(1.f - s1, 0.f), t2 = fmaxf(1.f - s2, 0.f);
            cf = v * ((s1 * s1 - t1 * t1) + (s2 * s2 - t2 * t2));
            s1 = b2f(Sg[(size_t)i * NN + j]) * imgi;
            s2 = b2f(Sg[(size_t)j * NN + i]) * ((float)NN / rsg[j]);
            t1 = fmaxf(1.f - s1, 0.f);
            t2 = fmaxf(1.f - s2, 0.f);
            cg = v * ((s1 * s1 - t1 * t1) + (s2 * s2 - t2 * t2));
        }
    }
    float tf = block_sum(cf, sbuf);
    float tg = block_sum(cg, sbuf);
    if (threadIdx.x == 0) {
        int bank = (blockIdx.x & 15) * 3;
        atomicAdd(&acc[bank + 0], (double)(0.25f * tf));
        atomicAdd(&acc[bank + 1], (double)(0.25f * tg));
    }
}

__global__ void finalize_kernel(const double* __restrict__ acc, float* __restrict__ out) {
    if (threadIdx.x == 0) {
        double a0 = 0.0, a1 = 0.0, a2 = 0.0;
        for (int b = 0; b < 16; ++b) {
            a0 += acc[b * 3 + 0];
            a1 += acc[b * 3 + 1];
            a2 += acc[b * 3 + 2];
        }
        double denom = (double)NN * (double)(NN - 1);
        double rcf = a0 / denom, rcg = a1 / denom;
        double rc = 0.5 * (rcf + rcg);
        double kl = a2 / (double)NN;
        out[0] = (float)rc;
        out[1] = (float)kl;
        out[2] = (float)(rc + kl);
    }
}

extern "C" void kernel_launch(void* const* d_in, const int* in_sizes, int n_in, void* d_out,
                              int out_size, void* d_ws, size_t ws_size, hipStream_t stream) {
    const float* s_f = (const float*)d_in[0];
    const float* s_g = (const float*)d_in[1];
    const float* t_g = (const float*)d_in[2];
    const int* idx = (const int*)d_in[3];
    float* out = (float*)d_out;

    char* base = (char*)d_ws;
    size_t off = 0;
    auto alloc = [&](size_t b) {
        char* p = base + off;
        off = (off + b + 255) & ~(size_t)255;
        return p;
    };
    double* acc = (double*)alloc(16 * 3 * 8);  // 16 banks x 3 doubles
    float* rowsum_f = (float*)alloc(NN * 4);
    float* rowsum_g = (float*)alloc(NN * 4);
    int* deg = (int*)alloc(NN * 4);
    size_t zero_bytes = off;  // acc + rowsums + deg zeroed each call
    u16* tb = (u16*)alloc((size_t)NN * 1024 * 2);
    u16* fb = (u16*)alloc((size_t)NN * 512 * 2);
    u16* gb = (u16*)alloc((size_t)NN * 512 * 2);
    float* ss_t = (float*)alloc(NN * 4);
    float* ss_f = (float*)alloc(NN * 4);
    float* ss_g = (float*)alloc(NN * 4);
    u16* WP = (u16*)alloc((size_t)NN * NN * 2);
    u16* Sf = (u16*)alloc((size_t)NN * NN * 2);
    u16* Sg = (u16*)alloc((size_t)NN * NN * 2);
    int* topk = (int*)alloc(NN * 10 * 4);
    int* nbr = (int*)alloc(NN * 10 * 4);
    float* tvals = (float*)alloc(NN * 10 * 4);
    int* hcols = (int*)alloc(NN * 50 * 4);
    float* hvals = (float*)alloc(NN * 50 * 4);

    hipMemsetAsync(d_ws, 0, zero_bytes, stream);

    normalize_kernel<1024><<<NN, 256, 0, stream>>>(t_g, tb, ss_t);
    normalize_kernel<512><<<NN, 256, 0, stream>>>(s_f, fb, ss_f);
    normalize_kernel<512><<<NN, 256, 0, stream>>>(s_g, gb, ss_g);

    gram_merged<<<1584, 256, 0, stream>>>(tb, fb, gb, ss_t, ss_f, ss_g, WP, Sf, Sg,
                                          rowsum_f, rowsum_g);

    topk_kernel<<<NN, 256, 0, stream>>>(WP, idx, topk);
    mutual_kernel<<<(NN * 10 + 255) / 256, 256, 0, stream>>>(topk, nbr, deg);
    tilda_kernel<<<(NN * 10 + 255) / 256, 256, 0, stream>>>(nbr, deg, tvals);
    hat_kernel<<<(NN * 5 + 255) / 256, 256, 0, stream>>>(topk, nbr, tvals, hcols, hvals);

    fused_dense_kernel<<<NN, 256, 0, stream>>>(Sf, Sg, WP, rowsum_f, rowsum_g, acc);
    sparse_kernel<<<NN / 4, 256, 0, stream>>>(Sf, Sg, hcols, hvals, rowsum_f, rowsum_g, acc);
    finalize_kernel<<<1, 64, 0, stream>>>(acc, out);
}

// Round 8
// 194.707 us; speedup vs baseline: 1.5025x; 1.1767x over previous
//
#include <hip/hip_runtime.h>
#include <hip/hip_bf16.h>

#define NN 4096
typedef unsigned short u16;
typedef __bf16 bf16x8 __attribute__((ext_vector_type(8)));
typedef float f32x4 __attribute__((ext_vector_type(4)));
typedef u16 u16x8 __attribute__((ext_vector_type(8)));

typedef const __attribute__((address_space(1))) void* gptr_t;
typedef __attribute__((address_space(3))) void* lptr_t;

__device__ inline u16 bf16bits(float v) {
    __bf16 h = (__bf16)v;
    return __builtin_bit_cast(u16, h);
}
__device__ inline float bf16val(float v) {
    __bf16 h = (__bf16)v;
    return (float)h;
}
__device__ inline float b2f(u16 b) { return __uint_as_float(((unsigned)b) << 16); }

// ---------------- block reduction helper (256 threads / 4 waves) ----------------
__device__ inline float block_sum(float v, volatile float* sbuf) {
    int lane = threadIdx.x & 63, wv = threadIdx.x >> 6;
#pragma unroll
    for (int o = 32; o > 0; o >>= 1) v += __shfl_xor(v, o, 64);
    if (lane == 0) sbuf[wv] = v;
    __syncthreads();
    float r = sbuf[0] + sbuf[1] + sbuf[2] + sbuf[3];
    __syncthreads();
    return r;
}

// ---------------- normalize rows (float4), emit bf16 + sum-of-squares(bf16) ----------------
template <int D>
__global__ void normalize_kernel(const float* __restrict__ in, u16* __restrict__ outb,
                                 float* __restrict__ ssout) {
    __shared__ float sbuf[4];
    constexpr int NV = D / 4;
    int row = blockIdx.x, tid = threadIdx.x;
    const float4* x4 = (const float4*)(in + (size_t)row * D);
    float4 v = make_float4(0.f, 0.f, 0.f, 0.f);
    if (tid < NV) v = x4[tid];
    float s = v.x * v.x + v.y * v.y + v.z * v.z + v.w * v.w;
    float tot = block_sum(s, sbuf);
    float inv = 1.0f / fmaxf(sqrtf(tot), 1e-12f);
    float sb = 0.f;
    if (tid < NV) {
        float b0 = bf16val(v.x * inv), b1 = bf16val(v.y * inv);
        float b2 = bf16val(v.z * inv), b3 = bf16val(v.w * inv);
        ushort4 o;
        o.x = bf16bits(v.x * inv);
        o.y = bf16bits(v.y * inv);
        o.z = bf16bits(v.z * inv);
        o.w = bf16bits(v.w * inv);
        ((ushort4*)(outb + (size_t)row * D))[tid] = o;
        sb = b0 * b0 + b1 * b1 + b2 * b2 + b3 * b3;
    }
    float totb = block_sum(sb, sbuf);
    if (tid == 0) ssout[row] = totb;
}

// ---------------- merged symmetric Gram kernel, 128x128 tiles, 4 waves ----------------
// 1584 blocks = 3 segments x 528 triangle blocks (32x32 grid, bx>=by).
// Per-matrix XCD swizzle. K-loop: 3-buffer staging, counted vmcnt(4), ONE barrier
// per K-step (proof: each wave's lgkmcnt(0) precedes its arrival at barrier t+1,
// so STAGE(t+3)->buf[t%3] after barrier t+1 is race-free). NO atomics anywhere.
#define TS 132  // epilogue LDS tile row stride in u16
__launch_bounds__(256)
__global__ void gram_merged(const u16* __restrict__ tb, const u16* __restrict__ fb,
                            const u16* __restrict__ gb, const float* __restrict__ ss_t,
                            const float* __restrict__ ss_f, const float* __restrict__ ss_g,
                            u16* __restrict__ WP, u16* __restrict__ Sf, u16* __restrict__ Sg) {
    // staging: A bufs [0,12288) u16 (3 x 4096), B bufs [12288,24576); epilogue tile overlaps base.
    __shared__ __align__(16) u16 smem[24576];  // 49152 B

    int bid = blockIdx.x;
    int seg = (bid < 528) ? 0 : (bid < 1056 ? 1 : 2);
    int p = bid - seg * 528;
    int l = (p & 7) * 66 + (p >> 3);  // bijective XCD swizzle within segment
    int by = 0, rem = l;
    while (rem >= 32 - by) { rem -= 32 - by; ++by; }
    int bx = by + rem;

    const u16* X = (seg == 0) ? tb : (seg == 1 ? fb : gb);
    const float* ss = (seg == 0) ? ss_t : (seg == 1 ? ss_f : ss_g);
    u16* outp = (seg == 0) ? WP : (seg == 1 ? Sf : Sg);
    const int K = (seg == 0) ? 1024 : 512;
    const bool mode1 = (seg != 0);
    const bool offdiag = (bx != by);

    const int tid = threadIdx.x;
    const int wv = tid >> 6, lane = tid & 63;
    const int wr = wv >> 1, wc = wv & 1;
    const int brow = by * 128, bcol = bx * 128;
    const int r = lane & 15, kc = lane >> 4;
    const int crow = lane >> 2;       // staging: row within 16-row chunk
    const int koff = (lane & 3) * 8;  // staging: element offset (16B granule)

    f32x4 acc[4][4];
#pragma unroll
    for (int mi = 0; mi < 4; ++mi)
#pragma unroll
        for (int ni = 0; ni < 4; ++ni) acc[mi][ni] = (f32x4){0.f, 0.f, 0.f, 0.f};

    // stage one 128x32 A-tile + B-tile into buffer buf: 8 chunks each, 2 per wave.
    // per-wave vmem ops per STAGE call = 4 (vmcnt accounting below).
    auto STAGE = [&](int buf, int k0) {
#pragma unroll
        for (int cc = 0; cc < 2; ++cc) {
            int c = wv * 2 + cc;  // c in [0,8)
            const u16* ga = X + (size_t)(brow + c * 16 + crow) * K + k0 + koff;
            const u16* gbp = X + (size_t)(bcol + c * 16 + crow) * K + k0 + koff;
            __builtin_amdgcn_global_load_lds((gptr_t)ga, (lptr_t)&smem[buf * 4096 + c * 512], 16, 0, 0);
            __builtin_amdgcn_global_load_lds((gptr_t)gbp, (lptr_t)&smem[12288 + buf * 4096 + c * 512], 16, 0, 0);
        }
    };

    const int NT = K / 32;
    STAGE(0, 0);
    STAGE(1, 32);
    for (int t = 0; t < NT; ++t) {
        int cur = t % 3;
        // my 4 loads for buf[cur] complete (4 newer for t+1 stay in flight)
        if (t == NT - 1) asm volatile("s_waitcnt vmcnt(0)" ::: "memory");
        else             asm volatile("s_waitcnt vmcnt(4)" ::: "memory");
        __builtin_amdgcn_sched_barrier(0);
        __builtin_amdgcn_s_barrier();  // all waves' buf[cur] loads landed; prior reads done
        __builtin_amdgcn_sched_barrier(0);

        bf16x8 af[4], bfr[4];
#pragma unroll
        for (int mi = 0; mi < 4; ++mi)
            af[mi] = *(const bf16x8*)&smem[cur * 4096 + (wr * 64 + mi * 16 + r) * 32 + kc * 8];
#pragma unroll
        for (int ni = 0; ni < 4; ++ni)
            bfr[ni] = *(const bf16x8*)&smem[12288 + cur * 4096 + (wc * 64 + ni * 16 + r) * 32 + kc * 8];

        if (t + 2 < NT) STAGE((t + 2) % 3, (t + 2) * 32);  // overwrites buf[(t-1)%3], safe

        asm volatile("s_waitcnt lgkmcnt(0)" ::: "memory");  // frags in regs
        __builtin_amdgcn_sched_barrier(0);                  // rule #18 fence

#pragma unroll
        for (int mi = 0; mi < 4; ++mi)
#pragma unroll
            for (int ni = 0; ni < 4; ++ni)
                acc[mi][ni] = __builtin_amdgcn_mfma_f32_16x16x32_bf16(af[mi], bfr[ni], acc[mi][ni], 0, 0, 0);
    }
    __syncthreads();  // loop done everywhere; tile may overwrite staging LDS

    // epilogue: transform acc -> bf16 LDS tile (C/D layout col=lane&15, row=(lane>>4)*4+reg)
    u16* tile = smem;
    const int q = lane >> 4;
#pragma unroll
    for (int mi = 0; mi < 4; ++mi) {
#pragma unroll
        for (int v = 0; v < 4; ++v) {
            int rl = wr * 64 + mi * 16 + q * 4 + v;
            float ssi = ss[brow + rl];
#pragma unroll
            for (int ni = 0; ni < 4; ++ni) {
                int cl = wc * 64 + ni * 16 + r;
                float d2 = fmaxf(ssi + ss[bcol + cl] - 2.0f * acc[mi][ni][v], 0.f);
                float o = mode1 ? sqrtf(d2) : __expf(-d2);
                tile[rl * TS + cl] = bf16bits(o);
            }
        }
    }
    __syncthreads();

    // pass 1: coalesced writeout of tile rows (pure copy, no reductions)
    {
        int rl = tid >> 1, hf = tid & 1;
        const u16* srow = &tile[rl * TS + hf * 64];
        u16* drow = outp + (size_t)(brow + rl) * NN + bcol + hf * 64;
#pragma unroll
        for (int i = 0; i < 8; ++i) {
            ushort4 aa = *(const ushort4*)(srow + i * 8);
            ushort4 bb = *(const ushort4*)(srow + i * 8 + 4);
            u16x8 pk = {aa.x, aa.y, aa.z, aa.w, bb.x, bb.y, bb.z, bb.w};
            *(u16x8*)(drow + i * 8) = pk;
        }
    }

    // pass 2 (off-diagonal blocks): transposed writeout
    if (offdiag) {
        int c = tid >> 1, hf = tid & 1;
        u16* drow = outp + (size_t)(bcol + c) * NN + brow + hf * 64;
#pragma unroll
        for (int s = 0; s < 8; ++s) {
            u16 g[8];
#pragma unroll
            for (int u = 0; u < 8; ++u) g[u] = tile[(hf * 64 + s * 8 + u) * TS + c];
            u16x8 pk = {g[0], g[1], g[2], g[3], g[4], g[5], g[6], g[7]};
            *(u16x8*)(drow + s * 8) = pk;
        }
    }
}

// ---------------- top-10 per row of W_P (bf16, ushort8 loads), same-id override ----------------
__global__ void topk_kernel(const u16* __restrict__ WP, const int* __restrict__ idx,
                            int* __restrict__ topk) {
    __shared__ unsigned long long sred[4];
    __shared__ unsigned long long sbest;
    int row = blockIdx.x, tid = threadIdx.x;
    int myid = idx[row];
    const u16x8* W8 = (const u16x8*)(WP + (size_t)row * NN);
    const int4* idx4 = (const int4*)idx;
    unsigned key[16];
#pragma unroll
    for (int a = 0; a < 2; ++a) {
        u16x8 w = W8[a * 256 + tid];
        int4 iA = idx4[a * 512 + tid * 2];
        int4 iB = idx4[a * 512 + tid * 2 + 1];
        int ids[8] = {iA.x, iA.y, iA.z, iA.w, iB.x, iB.y, iB.z, iB.w};
#pragma unroll
        for (int c = 0; c < 8; ++c)
            key[a * 8 + c] = (ids[c] == myid) ? 0x3F800000u : (((unsigned)w[c]) << 16);
    }
    int lane = tid & 63, wv = tid >> 6;
    for (int it = 0; it < 10; ++it) {
        unsigned long long best = 0;
#pragma unroll
        for (int a = 0; a < 2; ++a)
#pragma unroll
            for (int c = 0; c < 8; ++c) {
                unsigned j = (unsigned)(a * 2048 + tid * 8 + c);
                unsigned long long pk =
                    ((unsigned long long)key[a * 8 + c] << 32) | (0xFFFFFFFFu - j);
                if (pk > best) best = pk;
            }
#pragma unroll
        for (int o = 32; o > 0; o >>= 1) {
            unsigned long long t = __shfl_xor(best, o, 64);
            if (t > best) best = t;
        }
        if (lane == 0) sred[wv] = best;
        __syncthreads();
        if (tid == 0) {
            unsigned long long b = sred[0];
            for (int w2 = 1; w2 < 4; ++w2)
                if (sred[w2] > b) b = sred[w2];
            sbest = b;
        }
        __syncthreads();
        unsigned jstar = 0xFFFFFFFFu - (unsigned)(sbest & 0xFFFFFFFFu);
        if (tid == 0) topk[row * 10 + it] = (int)jstar;
        if (((jstar >> 3) & 255u) == (unsigned)tid) {
            unsigned slot = ((jstar >> 11) << 3) | (jstar & 7u);
#pragma unroll
            for (int a = 0; a < 16; ++a)
                if ((unsigned)a == slot) key[a] = 0u;
        }
        __syncthreads();
    }
}

// ---------------- mutual-kNN adjacency: thread per (i,a); sentinel -1 slots ----------------
__global__ void mutual_kernel(const int* __restrict__ topk, int* __restrict__ nbr,
                              int* __restrict__ deg) {
    int gid = blockIdx.x * 256 + threadIdx.x;
    if (gid >= NN * 10) return;
    int i = gid / 10, a = gid - i * 10;
    int j = topk[i * 10 + a];
    bool mut = false;
#pragma unroll
    for (int b = 0; b < 10; ++b) mut = mut || (topk[j * 10 + b] == i);
    nbr[gid] = mut ? j : -1;
    if (mut) atomicAdd(&deg[i], 1);
}

// ---------------- W_C_tilda: thread per (m,a) ----------------
__global__ void tilda_kernel(const int* __restrict__ nbr, const int* __restrict__ deg,
                             float* __restrict__ tvals) {
    int gid = blockIdx.x * 256 + threadIdx.x;
    if (gid >= NN * 10) return;
    int m = gid / 10;
    int j = nbr[gid];
    if (j < 0) { tvals[gid] = 0.f; return; }
    int am[10], aj[10];
#pragma unroll
    for (int p = 0; p < 10; ++p) am[p] = nbr[m * 10 + p];
#pragma unroll
    for (int p = 0; p < 10; ++p) aj[p] = nbr[j * 10 + p];
    int cnt = 0;
#pragma unroll
    for (int p = 0; p < 10; ++p)
#pragma unroll
        for (int qq = 0; qq < 10; ++qq)
            cnt += (am[p] >= 0 && am[p] == aj[qq]) ? 1 : 0;
    int dm = deg[m];
    float dv = (float)(dm > 1 ? dm : 1);
    tvals[gid] = (float)cnt / dv;
}

// ---------------- W_C_hat: thread per (i,h); emit 10 slots verbatim ----------------
__global__ void hat_kernel(const int* __restrict__ topk, const int* __restrict__ nbr,
                           const float* __restrict__ tvals, int* __restrict__ hcols,
                           float* __restrict__ hvals) {
    int gid = blockIdx.x * 256 + threadIdx.x;
    if (gid >= NN * 5) return;
    int i = gid / 5, h = gid - i * 5;
    int m = topk[i * 10 + h];
#pragma unroll
    for (int a = 0; a < 10; ++a) {
        int j = nbr[m * 10 + a];
        int slot = i * 50 + h * 10 + a;
        hcols[slot] = j;
        hvals[slot] = (j >= 0) ? tvals[m * 10 + a] * 0.2f : 0.f;
    }
}

// ---------------- fused: rowsum (in-register) + logsumexp + RC dense + KL ----------------
// Also WRITES rowsum_f/g for sparse_kernel (gram no longer produces them).
// acc banks: 64 line-strided banks of 8 doubles (64B) to avoid cross-XCD line ping-pong.
__global__ void fused_dense_kernel(const u16* __restrict__ Sf, const u16* __restrict__ Sg,
                                   const u16* __restrict__ WP, float* __restrict__ rsf,
                                   float* __restrict__ rsg, double* __restrict__ acc) {
    __shared__ float sbuf[4];
    int row = blockIdx.x, tid = threadIdx.x;
    const u16x8* f8 = (const u16x8*)(Sf + (size_t)row * NN);
    const u16x8* g8 = (const u16x8*)(Sg + (size_t)row * NN);
    const u16x8* w8 = (const u16x8*)(WP + (size_t)row * NN);
    u16x8 fr[2], gr[2];
#pragma unroll
    for (int a = 0; a < 2; ++a) {
        fr[a] = f8[a * 256 + tid];
        gr[a] = g8[a * 256 + tid];
    }
    // row sums from the register-resident rows (replaces gram's atomic rowsum)
    float sf_ = 0.f, sg_ = 0.f;
#pragma unroll
    for (int a = 0; a < 2; ++a)
#pragma unroll
        for (int c = 0; c < 8; ++c) {
            sf_ += b2f(fr[a][c]);
            sg_ += b2f(gr[a][c]);
        }
    float rsum_f = block_sum(sf_, sbuf);
    float rsum_g = block_sum(sg_, sbuf);
    if (tid == 0) {
        rsf[row] = rsum_f;
        rsg[row] = rsum_g;
    }
    float imf = (float)NN / rsum_f;
    float img = (float)NN / rsum_g;
    float vf[16], vg[16];
#pragma unroll
    for (int a = 0; a < 2; ++a)
#pragma unroll
        for (int c = 0; c < 8; ++c) {
            vf[a * 8 + c] = b2f(fr[a][c]) * imf;
            vg[a * 8 + c] = b2f(gr[a][c]) * img;
        }
    float ef = 0.f, eg = 0.f;
#pragma unroll
    for (int a = 0; a < 16; ++a) {
        ef += __expf(-vf[a]);
        eg += __expf(-vg[a]);
    }
    float lf = logf(block_sum(ef, sbuf));
    float lg = logf(block_sum(eg, sbuf));
    u16x8 wr2[2];
#pragma unroll
    for (int a = 0; a < 2; ++a) wr2[a] = w8[a * 256 + tid];
    float af = 0.f, ag = 0.f, akl = 0.f;
#pragma unroll
    for (int a = 0; a < 2; ++a) {
#pragma unroll
        for (int c = 0; c < 8; ++c) {
            int j = a * 2048 + tid * 8 + c;
            float wp = b2f(wr2[a][c]);
            float sf = vf[a * 8 + c], sg = vg[a * 8 + c];
            if (j != row) {
                float t = fmaxf(1.f - sf, 0.f);
                float pu = t * t;
                float gq = sf * sf - pu;
                af += pu + 0.5f * gq * wp;
                t = fmaxf(1.f - sg, 0.f);
                pu = t * t;
                gq = sg * sg - pu;
                ag += pu + 0.5f * gq * wp;
            }
            float lq = -sf - lf;
            float lp = -sg - lg;
            float pp = __expf(lp);
            akl += pp * (lp - lq);
        }
    }
    float tf = block_sum(af, sbuf);
    float tg2 = block_sum(ag, sbuf);
    float tk = block_sum(akl, sbuf);
    if (tid == 0) {
        int bank = (row & 63) * 8;  // 64B stride: one cache line per bank
        atomicAdd(&acc[bank + 0], (double)tf);
        atomicAdd(&acc[bank + 1], (double)tg2);
        atomicAdd(&acc[bank + 2], (double)tk);
    }
}

// ---------------- sparse W_C correction: wave per row, lanes 0..49 over hat slots ----------------
__global__ void sparse_kernel(const u16* __restrict__ Sf, const u16* __restrict__ Sg,
                              const int* __restrict__ hcols, const float* __restrict__ hvals,
                              const float* __restrict__ rsf, const float* __restrict__ rsg,
                              double* __restrict__ acc) {
    __shared__ float sbuf[4];
    int lane = threadIdx.x & 63, wv = threadIdx.x >> 6;
    int i = blockIdx.x * 4 + wv;
    float cf = 0.f, cg = 0.f;
    if (lane < 50) {
        int j = hcols[i * 50 + lane];
        if (j >= 0 && j != i) {
            float v = hvals[i * 50 + lane];
            float imfi = (float)NN / rsf[i];
            float imgi = (float)NN / rsg[i];
            float s1 = b2f(Sf[(size_t)i * NN + j]) * imfi;
            float s2 = b2f(Sf[(size_t)j * NN + i]) * ((float)NN / rsf[j]);
            float t1 = fmaxf(1.f - s1, 0.f), t2 = fmaxf(1.f - s2, 0.f);
            cf = v * ((s1 * s1 - t1 * t1) + (s2 * s2 - t2 * t2));
            s1 = b2f(Sg[(size_t)i * NN + j]) * imgi;
            s2 = b2f(Sg[(size_t)j * NN + i]) * ((float)NN / rsg[j]);
            t1 = fmaxf(1.f - s1, 0.f);
            t2 = fmaxf(1.f - s2, 0.f);
            cg = v * ((s1 * s1 - t1 * t1) + (s2 * s2 - t2 * t2));
        }
    }
    float tf = block_sum(cf, sbuf);
    float tg = block_sum(cg, sbuf);
    if (threadIdx.x == 0) {
        int bank = (blockIdx.x & 63) * 8;
        atomicAdd(&acc[bank + 0], (double)(0.25f * tf));
        atomicAdd(&acc[bank + 1], (double)(0.25f * tg));
    }
}

__global__ void finalize_kernel(const double* __restrict__ acc, float* __restrict__ out) {
    if (threadIdx.x == 0) {
        double a0 = 0.0, a1 = 0.0, a2 = 0.0;
        for (int b = 0; b < 64; ++b) {
            a0 += acc[b * 8 + 0];
            a1 += acc[b * 8 + 1];
            a2 += acc[b * 8 + 2];
        }
        double denom = (double)NN * (double)(NN - 1);
        double rcf = a0 / denom, rcg = a1 / denom;
        double rc = 0.5 * (rcf + rcg);
        double kl = a2 / (double)NN;
        out[0] = (float)rc;
        out[1] = (float)kl;
        out[2] = (float)(rc + kl);
    }
}

extern "C" void kernel_launch(void* const* d_in, const int* in_sizes, int n_in, void* d_out,
                              int out_size, void* d_ws, size_t ws_size, hipStream_t stream) {
    const float* s_f = (const float*)d_in[0];
    const float* s_g = (const float*)d_in[1];
    const float* t_g = (const float*)d_in[2];
    const int* idx = (const int*)d_in[3];
    float* out = (float*)d_out;

    char* base = (char*)d_ws;
    size_t off = 0;
    auto alloc = [&](size_t b) {
        char* p = base + off;
        off = (off + b + 255) & ~(size_t)255;
        return p;
    };
    double* acc = (double*)alloc(64 * 8 * 8);  // 64 line-strided banks x 8 doubles
    int* deg = (int*)alloc(NN * 4);
    size_t zero_bytes = off;  // acc + deg zeroed each call
    float* rowsum_f = (float*)alloc(NN * 4);   // written by fused_dense (no pre-zero needed)
    float* rowsum_g = (float*)alloc(NN * 4);
    u16* tb = (u16*)alloc((size_t)NN * 1024 * 2);
    u16* fb = (u16*)alloc((size_t)NN * 512 * 2);
    u16* gb = (u16*)alloc((size_t)NN * 512 * 2);
    float* ss_t = (float*)alloc(NN * 4);
    float* ss_f = (float*)alloc(NN * 4);
    float* ss_g = (float*)alloc(NN * 4);
    u16* WP = (u16*)alloc((size_t)NN * NN * 2);
    u16* Sf = (u16*)alloc((size_t)NN * NN * 2);
    u16* Sg = (u16*)alloc((size_t)NN * NN * 2);
    int* topk = (int*)alloc(NN * 10 * 4);
    int* nbr = (int*)alloc(NN * 10 * 4);
    float* tvals = (float*)alloc(NN * 10 * 4);
    int* hcols = (int*)alloc(NN * 50 * 4);
    float* hvals = (float*)alloc(NN * 50 * 4);

    hipMemsetAsync(d_ws, 0, zero_bytes, stream);

    normalize_kernel<1024><<<NN, 256, 0, stream>>>(t_g, tb, ss_t);
    normalize_kernel<512><<<NN, 256, 0, stream>>>(s_f, fb, ss_f);
    normalize_kernel<512><<<NN, 256, 0, stream>>>(s_g, gb, ss_g);

    gram_merged<<<1584, 256, 0, stream>>>(tb, fb, gb, ss_t, ss_f, ss_g, WP, Sf, Sg);

    topk_kernel<<<NN, 256, 0, stream>>>(WP, idx, topk);
    mutual_kernel<<<(NN * 10 + 255) / 256, 256, 0, stream>>>(topk, nbr, deg);
    tilda_kernel<<<(NN * 10 + 255) / 256, 256, 0, stream>>>(nbr, deg, tvals);
    hat_kernel<<<(NN * 5 + 255) / 256, 256, 0, stream>>>(topk, nbr, tvals, hcols, hvals);

    fused_dense_kernel<<<NN, 256, 0, stream>>>(Sf, Sg, WP, rowsum_f, rowsum_g, acc);
    sparse_kernel<<<NN / 4, 256, 0, stream>>>(Sf, Sg, hcols, hvals, rowsum_f, rowsum_g, acc);
    finalize_kernel<<<1, 64, 0, stream>>>(acc, out);
}